// Round 5
// baseline (127.353 us; speedup 1.0000x reference)
//
#include <hip/hip_runtime.h>

#define KK 8
#define CC 16

typedef int   vint4   __attribute__((ext_vector_type(4)));
typedef float vfloat4 __attribute__((ext_vector_type(4)));

// ---- Pass 1: global absmax of features (for i8 quantization scale) ----
__global__ void amax_kernel(const float* __restrict__ f, unsigned int* __restrict__ amax,
                            int n) {
    int tid = blockIdx.x * blockDim.x + threadIdx.x;
    int stride = gridDim.x * blockDim.x;
    float m = 0.f;
    for (int i = tid; i < n; i += stride) m = fmaxf(m, fabsf(f[i]));
#pragma unroll
    for (int off = 32; off; off >>= 1) m = fmaxf(m, __shfl_down(m, off, 64));
    __shared__ float s[4];
    int lane = threadIdx.x & 63, w = threadIdx.x >> 6;
    if (lane == 0) s[w] = m;
    __syncthreads();
    if (threadIdx.x == 0) {
        float mm = fmaxf(fmaxf(s[0], s[1]), fmaxf(s[2], s[3]));
        atomicMax(amax, __float_as_uint(mm));  // positive floats order as uints
    }
}

// ---- Pass 2: features (C,P) f32 -> (P,C) i8 records (16B/point) + inv_r2 ----
__global__ void prep_kernel(const float* __restrict__ f,
                            const float* __restrict__ radii,
                            const unsigned int* __restrict__ amax_p,
                            unsigned int* __restrict__ ft8,   // P x 4 uints
                            float* __restrict__ inv_r2, int P) {
    int p = blockIdx.x * blockDim.x + threadIdx.x;
    if (p >= P) return;
    float qs = 127.0f / __uint_as_float(*amax_p);
    float r = radii[p];
    inv_r2[p] = 1.0f / (r * r);
    unsigned int w[4];
#pragma unroll
    for (int j = 0; j < 4; ++j) {
        unsigned int b0 = (unsigned int)(__float2int_rn(f[(size_t)(4 * j + 0) * P + p] * qs)) & 0xFFu;
        unsigned int b1 = (unsigned int)(__float2int_rn(f[(size_t)(4 * j + 1) * P + p] * qs)) & 0xFFu;
        unsigned int b2 = (unsigned int)(__float2int_rn(f[(size_t)(4 * j + 2) * P + p] * qs)) & 0xFFu;
        unsigned int b3 = (unsigned int)(__float2int_rn(f[(size_t)(4 * j + 3) * P + p] * qs)) & 0xFFu;
        w[j] = b0 | (b1 << 8) | (b2 << 16) | (b3 << 24);
    }
    uint4* dst = (uint4*)(ft8 + (size_t)p * 4);
    dst[0] = make_uint4(w[0], w[1], w[2], w[3]);
}

// ---- Pass 3: render. 4 lanes per pixel; lane q owns channels [4q,4q+4).
// Hot gather set = 3.2MB i8 table + 0.8MB inv_r2 ~= fits per-XCD L2.
__global__ void render_kernel(const int* __restrict__ idx,
                              const float* __restrict__ dists,
                              const float* __restrict__ inv_r2,
                              const unsigned int* __restrict__ ft8,
                              const unsigned int* __restrict__ amax_p,
                              float* __restrict__ out, int npix) {
    int tid = blockIdx.x * blockDim.x + threadIdx.x;
    int pix = tid >> 2;
    int q = tid & 3;
    if (pix >= npix) return;

    float dsc = __uint_as_float(*amax_p) * (1.0f / 127.0f);

    const vint4* ip = (const vint4*)(idx + (size_t)pix * KK);
    const vfloat4* dp = (const vfloat4*)(dists + (size_t)pix * KK);
    vint4 i0 = __builtin_nontemporal_load(ip);
    vint4 i1 = __builtin_nontemporal_load(ip + 1);
    vfloat4 dv0 = __builtin_nontemporal_load(dp);
    vfloat4 dv1 = __builtin_nontemporal_load(dp + 1);
    int ids[KK] = {i0.x, i0.y, i0.z, i0.w, i1.x, i1.y, i1.z, i1.w};
    float ds[KK] = {dv0.x, dv0.y, dv0.z, dv0.w, dv1.x, dv1.y, dv1.z, dv1.w};

    float ir2[KK];
    unsigned int pk[KK];
    float vld[KK];
#pragma unroll
    for (int k = 0; k < KK; ++k) {
        int id = ids[k];
        int sid = id < 0 ? 0 : id;
        vld[k] = id < 0 ? 0.0f : 1.0f;
        ir2[k] = inv_r2[sid];
        pk[k] = ft8[(size_t)sid * 4 + q];   // 4 lanes x 4B consecutive = 16B/record
    }

    float a0 = 0.f, a1 = 0.f, a2 = 0.f, a3 = 0.f;
    float T = 1.0f;
#pragma unroll
    for (int k = 0; k < KK; ++k) {
        float w = (1.0f - ds[k] * ir2[k]) * vld[k];
        float a = (w * T) * dsc;
        T *= (1.0f - w);
        unsigned int p = pk[k];
        a0 += a * (float)((int)(p << 24) >> 24);
        a1 += a * (float)((int)(p << 16) >> 24);
        a2 += a * (float)((int)(p << 8) >> 24);
        a3 += a * (float)((int)p >> 24);
    }

    vfloat4* op = (vfloat4*)(out + (size_t)pix * CC + q * 4);
    vfloat4 res = {a0, a1, a2, a3};
    __builtin_nontemporal_store(res, op);
}

extern "C" void kernel_launch(void* const* d_in, const int* in_sizes, int n_in,
                              void* d_out, int out_size, void* d_ws, size_t ws_size,
                              hipStream_t stream) {
    const int* idx = (const int*)d_in[0];
    const float* dists = (const float*)d_in[1];
    const float* radii = (const float*)d_in[2];
    const float* features = (const float*)d_in[3];
    float* out = (float*)d_out;

    int P = in_sizes[2];            // 200000
    int nfeat = in_sizes[3];        // C*P = 3.2M
    int npix = in_sizes[0] / KK;    // B*H*W = 1048576

    unsigned int* ft8 = (unsigned int*)d_ws;                       // P*16B = 3.2MB
    float* inv_r2 = (float*)((char*)d_ws + (size_t)P * 16);        // +800KB
    unsigned int* amax = (unsigned int*)((char*)d_ws + (size_t)P * 20);

    hipMemsetAsync(amax, 0, 4, stream);
    amax_kernel<<<1024, 256, 0, stream>>>(features, amax, nfeat);
    prep_kernel<<<(P + 255) / 256, 256, 0, stream>>>(features, radii, amax, ft8, inv_r2, P);

    int nthreads = npix * 4;
    render_kernel<<<(nthreads + 255) / 256, 256, 0, stream>>>(
        idx, dists, inv_r2, ft8, amax, out, npix);
}

// Round 6
// 120.335 us; speedup vs baseline: 1.0583x; 1.0583x over previous
//
#include <hip/hip_runtime.h>

#define KK 8
#define CC 16

typedef int   vint4   __attribute__((ext_vector_type(4)));
typedef float vfloat4 __attribute__((ext_vector_type(4)));

// Record: 20B = 16 x i8 features + f32 inv_r2. Packed 3 records per 64B
// cache line (3*20=60, 4B pad) so one fragment touches EXACTLY one line.
static __device__ __forceinline__ size_t rec_base(int p) {
    int grp = p / 3;          // compiler: magic-mul
    int lane = p - grp * 3;
    return (size_t)grp * 64 + (size_t)lane * 20;
}

// ---- Pass 1: global absmax of features (for i8 quantization scale) ----
__global__ void amax_kernel(const float* __restrict__ f, unsigned int* __restrict__ amax,
                            int n) {
    int tid = blockIdx.x * blockDim.x + threadIdx.x;
    int stride = gridDim.x * blockDim.x;
    float m = 0.f;
    for (int i = tid; i < n; i += stride) m = fmaxf(m, fabsf(f[i]));
#pragma unroll
    for (int off = 32; off; off >>= 1) m = fmaxf(m, __shfl_down(m, off, 64));
    __shared__ float s[4];
    int lane = threadIdx.x & 63, w = threadIdx.x >> 6;
    if (lane == 0) s[w] = m;
    __syncthreads();
    if (threadIdx.x == 0) {
        float mm = fmaxf(fmaxf(s[0], s[1]), fmaxf(s[2], s[3]));
        atomicMax(amax, __float_as_uint(mm));  // positive floats order as uints
    }
}

// ---- Pass 2: build packed records ----
__global__ void prep_kernel(const float* __restrict__ f,
                            const float* __restrict__ radii,
                            const unsigned int* __restrict__ amax_p,
                            char* __restrict__ tab, int P) {
    int p = blockIdx.x * blockDim.x + threadIdx.x;
    if (p >= P) return;
    float qs = 127.0f / __uint_as_float(*amax_p);
    float r = radii[p];
    char* rec = tab + rec_base(p);
#pragma unroll
    for (int j = 0; j < 4; ++j) {
        unsigned int b0 = (unsigned int)(__float2int_rn(f[(size_t)(4 * j + 0) * P + p] * qs)) & 0xFFu;
        unsigned int b1 = (unsigned int)(__float2int_rn(f[(size_t)(4 * j + 1) * P + p] * qs)) & 0xFFu;
        unsigned int b2 = (unsigned int)(__float2int_rn(f[(size_t)(4 * j + 2) * P + p] * qs)) & 0xFFu;
        unsigned int b3 = (unsigned int)(__float2int_rn(f[(size_t)(4 * j + 3) * P + p] * qs)) & 0xFFu;
        *(unsigned int*)(rec + 4 * j) = b0 | (b1 << 8) | (b2 << 16) | (b3 << 24);
    }
    *(float*)(rec + 16) = 1.0f / (r * r);
}

// ---- Pass 3: render. 4 lanes per pixel; lane q owns channels [4q,4q+4).
// One cache line per fragment: features dword at base+4q (consecutive across
// quad), ir2 f32 at base+16 (quad-uniform -> broadcast merge, same line).
__global__ void render_kernel(const int* __restrict__ idx,
                              const float* __restrict__ dists,
                              const char* __restrict__ tab,
                              const unsigned int* __restrict__ amax_p,
                              float* __restrict__ out, int npix) {
    int tid = blockIdx.x * blockDim.x + threadIdx.x;
    int pix = tid >> 2;
    int q = tid & 3;
    if (pix >= npix) return;

    float dsc = __uint_as_float(*amax_p) * (1.0f / 127.0f);

    const vint4* ip = (const vint4*)(idx + (size_t)pix * KK);
    const vfloat4* dp = (const vfloat4*)(dists + (size_t)pix * KK);
    vint4 i0 = __builtin_nontemporal_load(ip);
    vint4 i1 = __builtin_nontemporal_load(ip + 1);
    vfloat4 dv0 = __builtin_nontemporal_load(dp);
    vfloat4 dv1 = __builtin_nontemporal_load(dp + 1);
    int ids[KK] = {i0.x, i0.y, i0.z, i0.w, i1.x, i1.y, i1.z, i1.w};
    float ds[KK] = {dv0.x, dv0.y, dv0.z, dv0.w, dv1.x, dv1.y, dv1.z, dv1.w};

    float ir2[KK];
    unsigned int pk[KK];
    float vld[KK];
#pragma unroll
    for (int k = 0; k < KK; ++k) {
        int id = ids[k];
        int sid = id < 0 ? 0 : id;
        vld[k] = id < 0 ? 0.0f : 1.0f;
        const char* rec = tab + rec_base(sid);
        pk[k] = *(const unsigned int*)(rec + q * 4);
        ir2[k] = *(const float*)(rec + 16);
    }

    float a0 = 0.f, a1 = 0.f, a2 = 0.f, a3 = 0.f;
    float T = 1.0f;
#pragma unroll
    for (int k = 0; k < KK; ++k) {
        float w = (1.0f - ds[k] * ir2[k]) * vld[k];
        float a = (w * T) * dsc;
        T *= (1.0f - w);
        unsigned int p = pk[k];
        a0 += a * (float)((int)(p << 24) >> 24);
        a1 += a * (float)((int)(p << 16) >> 24);
        a2 += a * (float)((int)(p << 8) >> 24);
        a3 += a * (float)((int)p >> 24);
    }

    vfloat4* op = (vfloat4*)(out + (size_t)pix * CC + q * 4);
    vfloat4 res = {a0, a1, a2, a3};
    __builtin_nontemporal_store(res, op);
}

extern "C" void kernel_launch(void* const* d_in, const int* in_sizes, int n_in,
                              void* d_out, int out_size, void* d_ws, size_t ws_size,
                              hipStream_t stream) {
    const int* idx = (const int*)d_in[0];
    const float* dists = (const float*)d_in[1];
    const float* radii = (const float*)d_in[2];
    const float* features = (const float*)d_in[3];
    float* out = (float*)d_out;

    int P = in_sizes[2];            // 200000
    int nfeat = in_sizes[3];        // C*P = 3.2M
    int npix = in_sizes[0] / KK;    // B*H*W = 1048576

    char* tab = (char*)d_ws;        // ceil(P/3)*64 = ~4.27MB
    size_t tab_bytes = (size_t)((P + 2) / 3) * 64;
    unsigned int* amax = (unsigned int*)(tab + tab_bytes);

    hipMemsetAsync(amax, 0, 4, stream);
    amax_kernel<<<1024, 256, 0, stream>>>(features, amax, nfeat);
    prep_kernel<<<(P + 255) / 256, 256, 0, stream>>>(features, radii, amax, tab, P);

    int nthreads = npix * 4;
    render_kernel<<<(nthreads + 255) / 256, 256, 0, stream>>>(
        idx, dists, tab, amax, out, npix);
}

// Round 7
// 79.854 us; speedup vs baseline: 1.5948x; 1.5069x over previous
//
#include <hip/hip_runtime.h>

#define KK 8
#define CC 16

typedef int   vint4   __attribute__((ext_vector_type(4)));
typedef float vfloat4 __attribute__((ext_vector_type(4)));
typedef unsigned int vuint4 __attribute__((ext_vector_type(4)));

// Record: 20B = 16 x i8 features + meta dword {bf16 inv_r2 | bf16 scale<<16}.
// 3 records per 64B line (60B + 4B pad): a record NEVER straddles a line.
static __device__ __forceinline__ size_t rec_base(int p) {
    int grp = p / 3;          // magic-mul
    int lane = p - grp * 3;
    return (size_t)grp * 64 + (size_t)lane * 20;
}

static __device__ __forceinline__ unsigned short f32_to_bf16(float x) {
    unsigned int b = __float_as_uint(x);
    unsigned int r = b + 0x7FFFu + ((b >> 16) & 1u);
    return (unsigned short)(r >> 16);
}

// ---- Pass 1 (only prep pass): per-point scale + quantize + pack ----
__global__ void prep_kernel(const float* __restrict__ f,
                            const float* __restrict__ radii,
                            char* __restrict__ tab, int P) {
    int p = blockIdx.x * blockDim.x + threadIdx.x;
    if (p >= P) return;
    float v[CC];
    float am = 1e-20f;
#pragma unroll
    for (int c = 0; c < CC; ++c) {
        v[c] = f[(size_t)c * P + p];
        am = fmaxf(am, fabsf(v[c]));
    }
    // stored scale s = amax/127, rounded to bf16; quantize with the ROUNDED
    // value so dequant is its exact inverse (clamp covers round-down).
    unsigned short sc_b = f32_to_bf16(am * (1.0f / 127.0f));
    float s = __uint_as_float((unsigned int)sc_b << 16);
    float qs = 1.0f / s;
    unsigned int w[4];
#pragma unroll
    for (int j = 0; j < 4; ++j) {
        int q0 = __float2int_rn(v[4 * j + 0] * qs); q0 = max(-127, min(127, q0));
        int q1 = __float2int_rn(v[4 * j + 1] * qs); q1 = max(-127, min(127, q1));
        int q2 = __float2int_rn(v[4 * j + 2] * qs); q2 = max(-127, min(127, q2));
        int q3 = __float2int_rn(v[4 * j + 3] * qs); q3 = max(-127, min(127, q3));
        w[j] = ((unsigned int)q0 & 0xFFu) | (((unsigned int)q1 & 0xFFu) << 8) |
               (((unsigned int)q2 & 0xFFu) << 16) | (((unsigned int)q3 & 0xFFu) << 24);
    }
    float r = radii[p];
    unsigned short ir2_b = f32_to_bf16(1.0f / (r * r));
    unsigned int meta = (unsigned int)ir2_b | ((unsigned int)sc_b << 16);
    char* rec = tab + rec_base(p);
    *(unsigned int*)(rec + 0) = w[0];
    *(unsigned int*)(rec + 4) = w[1];
    *(unsigned int*)(rec + 8) = w[2];
    *(unsigned int*)(rec + 12) = w[3];
    *(unsigned int*)(rec + 16) = meta;
}

// ---- Pass 2: render. 2 lanes per pixel; lane h owns channels [8h, 8h+8).
// ONE dwordx4 gather per fragment per lane at rec+8h:
//   lane0: bytes 0-15  -> ch0-7 in .x/.y
//   lane1: bytes 8-23  -> ch8-15 in .x/.y, meta in .z (bytes 16-19)
// (always within one 64B line; byte 20-23 overreach stays inside the line).
// lane0 gets meta from its partner via one shuffle.
__global__ void render_kernel(const int* __restrict__ idx,
                              const float* __restrict__ dists,
                              const char* __restrict__ tab,
                              float* __restrict__ out, int npix) {
    int tid = blockIdx.x * blockDim.x + threadIdx.x;
    int pix = tid >> 1;
    int h = tid & 1;
    if (pix >= npix) return;

    const vint4* ip = (const vint4*)(idx + (size_t)pix * KK);
    const vfloat4* dp = (const vfloat4*)(dists + (size_t)pix * KK);
    vint4 i0 = __builtin_nontemporal_load(ip);
    vint4 i1 = __builtin_nontemporal_load(ip + 1);
    vfloat4 dv0 = __builtin_nontemporal_load(dp);
    vfloat4 dv1 = __builtin_nontemporal_load(dp + 1);
    int ids[KK] = {i0.x, i0.y, i0.z, i0.w, i1.x, i1.y, i1.z, i1.w};
    float ds[KK] = {dv0.x, dv0.y, dv0.z, dv0.w, dv1.x, dv1.y, dv1.z, dv1.w};

    vuint4 pk[KK];
    float vld[KK];
#pragma unroll
    for (int k = 0; k < KK; ++k) {
        int id = ids[k];
        int sid = id < 0 ? 0 : id;
        vld[k] = id < 0 ? 0.0f : 1.0f;
        pk[k] = *(const vuint4*)(tab + rec_base(sid) + 8 * h);
    }

    int mlane = ((tid & 63) | 1);  // odd lane of the pair holds meta in .z

    float a0 = 0.f, a1 = 0.f, a2 = 0.f, a3 = 0.f;
    float a4 = 0.f, a5 = 0.f, a6 = 0.f, a7 = 0.f;
    float T = 1.0f;
#pragma unroll
    for (int k = 0; k < KK; ++k) {
        unsigned int meta = (unsigned int)__shfl((int)pk[k].z, mlane, 64);
        float ir2 = __uint_as_float((meta & 0xFFFFu) << 16);
        float s = __uint_as_float(meta & 0xFFFF0000u);
        float w = (1.0f - ds[k] * ir2) * vld[k];
        float as = (w * T) * s;
        T *= (1.0f - w);
        unsigned int px = pk[k].x, py = pk[k].y;
        a0 += as * (float)((int)(px << 24) >> 24);
        a1 += as * (float)((int)(px << 16) >> 24);
        a2 += as * (float)((int)(px << 8) >> 24);
        a3 += as * (float)((int)px >> 24);
        a4 += as * (float)((int)(py << 24) >> 24);
        a5 += as * (float)((int)(py << 16) >> 24);
        a6 += as * (float)((int)(py << 8) >> 24);
        a7 += as * (float)((int)py >> 24);
    }

    float* ob = out + (size_t)pix * CC + 8 * h;
    vfloat4 r0 = {a0, a1, a2, a3};
    vfloat4 r1 = {a4, a5, a6, a7};
    __builtin_nontemporal_store(r0, (vfloat4*)ob);
    __builtin_nontemporal_store(r1, (vfloat4*)(ob + 4));
}

extern "C" void kernel_launch(void* const* d_in, const int* in_sizes, int n_in,
                              void* d_out, int out_size, void* d_ws, size_t ws_size,
                              hipStream_t stream) {
    const int* idx = (const int*)d_in[0];
    const float* dists = (const float*)d_in[1];
    const float* radii = (const float*)d_in[2];
    const float* features = (const float*)d_in[3];
    float* out = (float*)d_out;

    int P = in_sizes[2];            // 200000
    int npix = in_sizes[0] / KK;    // B*H*W = 1048576

    char* tab = (char*)d_ws;        // ceil(P/3)*64 = ~4.27MB

    prep_kernel<<<(P + 255) / 256, 256, 0, stream>>>(features, radii, tab, P);

    int nthreads = npix * 2;
    render_kernel<<<(nthreads + 255) / 256, 256, 0, stream>>>(
        idx, dists, tab, out, npix);
}